// Round 5
// baseline (767.600 us; speedup 1.0000x reference)
//
#include <hip/hip_runtime.h>
#include <hip/hip_cooperative_groups.h>
namespace cg = cooperative_groups;

#define N_NODES 50000
#define N_EDGES 600000
#define N_RELS  19
#define D_IN    128
#define D_HID   64
#define D_OUT   2
#define BSH     9                                   // src bucket = 512 nodes
#define NB      ((N_NODES + 511) >> 9)              // 98
#define NSEG    (NB * N_RELS)                       // 1862
#define SL_BLOCKS ((N_NODES + 63) / 64)             // 782
#define PREP_ELEMS (N_RELS * D_HID * D_IN + 64 * 64 + D_HID * D_IN)  // 167936
#define ZERO_INTS (319232 / 4)                      // seg_hist+gcnt+hist_dst
#define NAGG 12500                                  // 4 nodes per virtual block

typedef unsigned short u16;
typedef unsigned int   u32;
typedef __attribute__((ext_vector_type(8))) short sfrag;   // 8 bf16 (4 VGPRs)
typedef __attribute__((ext_vector_type(4))) float f32x4;   // 4 fp32 acc

__device__ __forceinline__ u16 f2bf(float f){
  union { float f; u32 i; } v; v.f = f;
  u32 r = v.i + 0x7fffu + ((v.i >> 16) & 1u);  // RNE
  return (u16)(r >> 16);
}
__device__ __forceinline__ float bf2f(u16 u){
  union { u32 i; float f; } v; v.i = ((u32)u) << 16; return v.f;
}
__device__ __forceinline__ u32 pack2(float lo, float hi){
  return (u32)f2bf(lo) | ((u32)f2bf(hi) << 16);
}

// Gather A-fragments + msgbuf slot atomic for one 128-edge tile (into registers).
__device__ __forceinline__ void gather_tile(
    const u16* __restrict__ featb, const int* __restrict__ src,
    const int* __restrict__ dst, const int* __restrict__ perm,
    int* __restrict__ cur_dst, int* __restrict__ srel,
    int ts, int c, int t0, int rel, int tid, int w4, int r16, int c4,
    sfrag (&aN)[2][4], int& nextPos){
  int vc = c - t0; if (vc > 128) vc = 128;
  #pragma unroll
  for (int mt = 0; mt < 2; ++mt) {
    int row = w4 * 32 + mt * 16 + r16;
    int rr = row < vc ? row : vc - 1;
    int s = src[perm[ts + t0 + rr]];
    const u16* ap = featb + (size_t)s * D_IN + c4 * 8;
    #pragma unroll
    for (int kk = 0; kk < 4; ++kk)
      aN[mt][kk] = *(const sfrag*)(ap + kk * 32);
  }
  nextPos = -1;
  if (tid < 128 && tid < vc) {
    int e = perm[ts + t0 + tid];
    nextPos = atomicAdd(&cur_dst[dst[e]], 1);
    srel[nextPos] = (src[e] << 5) | rel;
  }
}

// ONE cooperative kernel for the whole pipeline. Phases separated by grid.sync():
// P0 zero hists + weight transform     P1 feat->bf16 + seg/dst histograms
// P2 seg scan + dst slot allocation    P3 scatter edges into perm
// P4 layer-1: seg-per-block MFMA tiles (R3's verified k_se1) + self-loop GEMM
// P5 msg aggregation + relu + fused T2 (per-rel layer-2 transform, h1 never
//    leaves LDS; W2allT rows 38/39 carry loop2 -> out init)
// P6 layer-2 finish: srel-driven T2 gather, atomic-free out +=
__global__ __launch_bounds__(256, 4) void k_all(
    const float* __restrict__ feat, const float* __restrict__ W1,
    const float* __restrict__ loop1, const float* __restrict__ b1,
    const float* __restrict__ W2, const float* __restrict__ loop2,
    const float* __restrict__ b2, const int* __restrict__ src,
    const int* __restrict__ dst, const int* __restrict__ et,
    float* __restrict__ out, char* __restrict__ ws){
  // ---- workspace carve ----
  u16*   W1Tb     = (u16*)(ws);                   //  311296
  u16*   W2allT   = (u16*)(ws + 311296);          //    8192 (64x64)
  u16*   loop1Tb  = (u16*)(ws + 319488);          //   16384
  int*   seg_hist = (int*)(ws + 335872);          //  119168 (1862 x 64B) ┐
  int*   gcnt     = (int*)(ws + 455040);          //      64              ├ P0-zeroed
  int*   hist_dst = (int*)(ws + 455104);          //  200000              ┘
  int*   seg_off  = (int*)(ws + 655104);          //    7488
  int*   cur_seg  = (int*)(ws + 662592);          //  119168 (64B-padded)
  int*   dstart   = (int*)(ws + 781760);          //  200000
  int*   cur_dst  = (int*)(ws + 981760);          //  200000
  int*   perm     = (int*)(ws + 1181760);         // 2400000
  int*   srel     = (int*)(ws + 3581760);         // 2400000
  u16*   featb    = (u16*)(ws + 5981760);         // 12.8 MB
  u16*   agg1b    = (u16*)(ws + 18781760);        //  6.4 MB
  float* T2f      = (float*)(ws + 25181760);      //  8.0 MB (50000 x 40)
  u16*   msgbuf   = (u16*)(ws + 33181760);        // 76.8 MB -> 109981760 total

  __shared__ __align__(16) char smem[36864];
  cg::grid_group grid = cg::this_grid();
  const int tid = threadIdx.x, lane = tid & 63, w4 = tid >> 6;
  const int bid = blockIdx.x, G = gridDim.x;
  const int r16 = lane & 15, c4 = lane >> 4;
  const int gth = G * 256;

  // ================= P0: zero hists + weight transform =================
  for (int i = bid * 256 + tid; i < ZERO_INTS; i += gth) seg_hist[i] = 0;
  for (int idx = bid * 256 + tid; idx < PREP_ELEMS; idx += gth) {
    const int T1  = N_RELS * D_HID * D_IN;        // 155648
    const int T2c = T1 + 64 * 64;                 // 159744
    if (idx < T1) {
      int r = idx / (D_HID * D_IN);
      int t = idx - r * (D_HID * D_IN);
      int j = t >> 7, d = t & 127;
      W1Tb[idx] = f2bf(W1[(r * D_IN + d) * D_HID + j]);
    } else if (idx < T2c) {
      int k2 = idx - T1;
      int j = k2 >> 6, k = k2 & 63;
      float val = 0.f;
      if (j < N_RELS * D_OUT)      val = W2[((j >> 1) * D_HID + k) * D_OUT + (j & 1)];
      else if (j == 38)            val = loop2[k * 2];
      else if (j == 39)            val = loop2[k * 2 + 1];
      W2allT[k2] = f2bf(val);
    } else {
      int k2 = idx - T2c;
      int j = k2 >> 7, d = k2 & 127;
      loop1Tb[k2] = f2bf(loop1[d * D_HID + j]);
    }
  }
  grid.sync();

  // ================= P1: feat convert + histograms =================
  for (int i = bid * 256 + tid; i < N_NODES * D_IN / 4; i += gth) {
    float4 f = ((const float4*)feat)[i];
    uint2 p; p.x = pack2(f.x, f.y); p.y = pack2(f.z, f.w);
    ((uint2*)featb)[i] = p;
  }
  for (int e = bid * 256 + tid; e < N_EDGES; e += gth) {
    int key = (src[e] >> BSH) * N_RELS + et[e];
    atomicAdd(&seg_hist[key * 16], 1);
    atomicAdd(&hist_dst[dst[e]], 1);
  }
  grid.sync();

  // ================= P2: scans =================
  if (bid == 0) {                                 // segment scan (1 block)
    int* ps = (int*)smem;
    const int PER = (NSEG + 255) / 256;           // 8
    int lo = tid * PER, hi = lo + PER; if (hi > NSEG) hi = NSEG; if (lo > NSEG) lo = NSEG;
    int s = 0;
    for (int i = lo; i < hi; ++i) s += seg_hist[i * 16];
    ps[tid] = s;
    __syncthreads();
    if (tid == 0) { int a = 0; for (int j = 0; j < 256; ++j) { int x = ps[j]; ps[j] = a; a += x; } }
    __syncthreads();
    int eo = ps[tid];
    for (int i = lo; i < hi; ++i) {
      int cs = seg_hist[i * 16];
      seg_off[i] = eo; cur_seg[i * 16] = eo;
      eo += cs;
    }
    if (hi == NSEG) seg_off[NSEG] = eo;           // == N_EDGES
  } else if (bid <= 196) {                        // dst slot allocation
    int* wbase = (int*)smem;
    int n = (bid - 1) * 256 + tid;
    int vv = (n < N_NODES) ? hist_dst[n] : 0;
    int x = vv;
    #pragma unroll
    for (int o = 1; o < 64; o <<= 1) { int u = __shfl_up(x, o); if (lane >= o) x += u; }
    if (lane == 63) wbase[w4] = atomicAdd(gcnt, x);
    __syncthreads();
    int start = wbase[w4] + x - vv;
    if (n < N_NODES) { dstart[n] = start; cur_dst[n] = start; }
  }
  grid.sync();

  // ================= P3: scatter =================
  for (int e = bid * 256 + tid; e < N_EDGES; e += gth) {
    int key = (src[e] >> BSH) * N_RELS + et[e];
    int p = atomicAdd(&cur_seg[key * 16], 1);
    perm[p] = e;
  }
  grid.sync();

  // ================= P4: layer-1 edge GEMM + self-loop =================
  {
    u16 (*Bls)[136] = (u16(*)[136])smem;          // 17408 B
    u16 (*msgl)[72] = (u16(*)[72])(smem + 17408); // 18432 B
    int* posIds     = (int*)(smem + 35840);       //   512 B
    for (int v = bid; v < NSEG + SL_BLOCKS; v += G) {
      if (v >= NSEG) {                            // ---- self-loop ----
        int base = (v - NSEG) * 64;
        { int j = tid >> 2, sg = tid & 3;
          const uint4* g = (const uint4*)(loop1Tb + j * 128) + sg * 4;
          uint4* d = (uint4*)&Bls[j][sg * 32];
          d[0] = g[0]; d[1] = g[1]; d[2] = g[2]; d[3] = g[3]; }
        int arow = base + w4 * 16 + r16; if (arow >= N_NODES) arow = N_NODES - 1;
        sfrag aF[4];
        #pragma unroll
        for (int kk = 0; kk < 4; ++kk)
          aF[kk] = *(const sfrag*)(featb + (size_t)arow * D_IN + kk * 32 + c4 * 8);
        __syncthreads();
        #pragma unroll
        for (int ct = 0; ct < 4; ++ct) {
          f32x4 acc = {0.f, 0.f, 0.f, 0.f};
          #pragma unroll
          for (int kk = 0; kk < 4; ++kk) {
            sfrag bF = *(const sfrag*)&Bls[ct * 16 + r16][kk * 32 + c4 * 8];
            acc = __builtin_amdgcn_mfma_f32_16x16x32_bf16(aF[kk], bF, acc, 0, 0, 0);
          }
          int col = ct * 16 + r16;
          float bias = b1[col];
          #pragma unroll
          for (int reg = 0; reg < 4; ++reg) {
            float vv2 = acc[reg] + bias;
            float o = __shfl_xor(vv2, 1);
            if (!(lane & 1)) {
              int orow = w4 * 16 + c4 * 4 + reg;
              *(u32*)&msgl[orow][col] = pack2(vv2, o);
            }
          }
        }
        __syncthreads();
        { int row = tid >> 2, q = tid & 3;
          int n = base + row;
          if (n < N_NODES) {
            uint4 a0 = ((const uint4*)&msgl[row][0])[q * 2];
            uint4 a1 = ((const uint4*)&msgl[row][0])[q * 2 + 1];
            uint4* d = (uint4*)(agg1b + (size_t)n * D_HID + q * 16);
            d[0] = a0; d[1] = a1;
          } }
      } else {                                    // ---- segment path ----
        const int q8 = NSEG >> 3, r8 = NSEG & 7;  // bijective XCD chunk map
        int xcd = v & 7, cidx = v >> 3;
        int seg = (xcd < r8 ? xcd * (q8 + 1) : r8 * (q8 + 1) + (xcd - r8) * q8) + cidx;
        int ts = seg_off[seg], c = seg_off[seg + 1] - ts;
        if (c == 0) continue;
        int rel = seg - (seg / N_RELS) * N_RELS;
        { int j = tid >> 2, sg = tid & 3;         // B staged once per segment
          const uint4* g = (const uint4*)(W1Tb + ((size_t)rel * 64 + j) * 128) + sg * 4;
          uint4* d = (uint4*)&Bls[j][sg * 32];
          d[0] = g[0]; d[1] = g[1]; d[2] = g[2]; d[3] = g[3]; }
        sfrag aN[2][4]; int nextPos;
        gather_tile(featb, src, dst, perm, cur_dst, srel, ts, c, 0, rel,
                    tid, w4, r16, c4, aN, nextPos);
        __syncthreads();
        for (int t0 = 0; t0 < c; t0 += 128) {
          sfrag aC[2][4];
          #pragma unroll
          for (int mt = 0; mt < 2; ++mt)
            #pragma unroll
            for (int kk = 0; kk < 4; ++kk) aC[mt][kk] = aN[mt][kk];
          int curPos = nextPos;
          if (t0 + 128 < c)
            gather_tile(featb, src, dst, perm, cur_dst, srel, ts, c, t0 + 128, rel,
                        tid, w4, r16, c4, aN, nextPos);
          #pragma unroll
          for (int ct = 0; ct < 4; ++ct) {
            sfrag bF[4];
            #pragma unroll
            for (int kk = 0; kk < 4; ++kk)
              bF[kk] = *(const sfrag*)&Bls[ct * 16 + r16][kk * 32 + c4 * 8];
            #pragma unroll
            for (int mt = 0; mt < 2; ++mt) {
              f32x4 acc = {0.f, 0.f, 0.f, 0.f};
              #pragma unroll
              for (int kk = 0; kk < 4; ++kk)
                acc = __builtin_amdgcn_mfma_f32_16x16x32_bf16(aC[mt][kk], bF[kk], acc, 0, 0, 0);
              #pragma unroll
              for (int reg = 0; reg < 4; ++reg) {
                float vv2 = acc[reg];
                float o = __shfl_xor(vv2, 1);
                if (!(lane & 1)) {
                  int orow = w4 * 32 + mt * 16 + c4 * 4 + reg;
                  *(u32*)&msgl[orow][ct * 16 + r16] = pack2(vv2, o);
                }
              }
            }
          }
          if (tid < 128) posIds[tid] = curPos;
          __syncthreads();
          { int row = tid >> 1, half = tid & 1;
            int pos = posIds[row];
            if (pos >= 0) {
              const uint4* mr = (const uint4*)&msgl[row][half * 32];
              uint4* d = (uint4*)(msgbuf + (size_t)pos * D_HID + half * 32);
              d[0] = mr[0]; d[1] = mr[1]; d[2] = mr[2]; d[3] = mr[3];
            } }
          __syncthreads();
        }
      }
      __syncthreads();
    }
  }
  grid.sync();

  // ================= P5: aggregation + relu + fused T2 =================
  {
    u16   (*W2ls)[66] = (u16(*)[66])smem;           // 8448 B, pad kills conflicts
    float (*h1s)[68]  = (float(*)[68])(smem + 8448);
    for (int i = tid; i < 64 * 64; i += 256) W2ls[i >> 6][i & 63] = W2allT[i];
    __syncthreads();
    int h = lane >> 5, cc = lane & 31;
    for (int v = bid; v < NAGG; v += G) {
      int n = v * 4 + w4;
      int s = dstart[n], epos = s + hist_dst[n];
      float a0 = 0.f, a1 = 0.f;
      for (int i = s + h; i < epos; i += 2) {
        u32 mv = ((const u32*)msgbuf)[(size_t)i * 32 + cc];
        a0 += bf2f((u16)(mv & 0xffffu));
        a1 += bf2f((u16)(mv >> 16));
      }
      a0 += __shfl_down(a0, 32);
      a1 += __shfl_down(a1, 32);
      if (h == 0) {
        u32 sv = ((const u32*)agg1b)[(size_t)n * 32 + cc];
        float v0 = a0 + bf2f((u16)(sv & 0xffffu));
        float v1 = a1 + bf2f((u16)(sv >> 16));
        v0 = v0 > 0.f ? v0 : 0.f;
        v1 = v1 > 0.f ? v1 : 0.f;
        h1s[w4][2 * cc] = v0;
        h1s[w4][2 * cc + 1] = v1;                 // wave-private: no barrier needed
      }
      int j = lane;
      if (j < 40) {                               // T2 row: 64-wide LDS dot
        float acc = 0.f;
        #pragma unroll 8
        for (int k = 0; k < 64; ++k)
          acc += bf2f(W2ls[j][k]) * h1s[w4][k];
        if (j < 38) T2f[(size_t)n * 40 + j] = acc;
        else        out[n * 2 + (j - 38)] = acc + b2[j - 38];
      }
    }
  }
  grid.sync();

  // ================= P6: layer-2 finish =================
  for (int v = bid; v < NAGG; v += G) {
    int n = v * 4 + w4;
    int s = dstart[n], c = hist_dst[n];
    float ax = 0.f, ay = 0.f;
    for (int i = lane; i < c; i += 64) {
      int sr = srel[s + i];
      const float* p = T2f + (size_t)(sr >> 5) * 40 + (sr & 31) * 2;
      ax += p[0]; ay += p[1];
    }
    #pragma unroll
    for (int off = 32; off; off >>= 1) {
      ax += __shfl_down(ax, off);
      ay += __shfl_down(ay, off);
    }
    if (lane == 0) {
      out[n * 2]     += ax;
      out[n * 2 + 1] += ay;
    }
  }
}

extern "C" void kernel_launch(void* const* d_in, const int* in_sizes, int n_in,
                              void* d_out, int out_size, void* d_ws, size_t ws_size,
                              hipStream_t stream){
  const float* feat  = (const float*)d_in[0];
  const float* W1    = (const float*)d_in[1];
  const float* loop1 = (const float*)d_in[2];
  const float* b1    = (const float*)d_in[3];
  const float* W2    = (const float*)d_in[4];
  const float* loop2 = (const float*)d_in[5];
  const float* b2    = (const float*)d_in[6];
  const int* src     = (const int*)d_in[7];
  const int* dst     = (const int*)d_in[8];
  const int* et      = (const int*)d_in[9];
  float* out = (float*)d_out;
  char* wsb = (char*)d_ws;

  static int s_grid = 0;
  if (s_grid == 0) {
    int nb = 0, ncu = 0;
    hipOccupancyMaxActiveBlocksPerMultiprocessor(&nb, reinterpret_cast<const void*>(k_all), 256, 0);
    hipDeviceGetAttribute(&ncu, hipDeviceAttributeMultiprocessorCount, 0);
    if (nb < 1) nb = 1;
    if (ncu < 1) ncu = 256;
    long g = (long)nb * (long)ncu;
    if (g > 2048) g = 2048;
    g &= ~7L;                                     // multiple of 8 keeps XCD map intact
    if (g < 8) g = 8;
    s_grid = (int)g;
  }

  void* kargs[] = { (void*)&feat, (void*)&W1, (void*)&loop1, (void*)&b1,
                    (void*)&W2, (void*)&loop2, (void*)&b2, (void*)&src,
                    (void*)&dst, (void*)&et, (void*)&out, (void*)&wsb };
  hipLaunchCooperativeKernel(reinterpret_cast<void*>(k_all),
                             dim3(s_grid), dim3(256), kargs, 0, stream);
}

// Round 6
// 386.081 us; speedup vs baseline: 1.9882x; 1.9882x over previous
//
#include <hip/hip_runtime.h>

#define N_NODES 50000
#define N_EDGES 600000
#define N_RELS  19
#define D_IN    128
#define D_HID   64
#define D_OUT   2
#define BSH     9                                   // src bucket = 512 nodes
#define NB      ((N_NODES + 511) >> 9)              // 98
#define NSEG    (NB * N_RELS)                       // 1862
#define SL_BLOCKS ((N_NODES + 63) / 64)             // 782
#define PREP_ELEMS (N_RELS * D_HID * D_IN + 64 * 64 + D_HID * D_IN)  // 167936
#define PREP_BLOCKS ((PREP_ELEMS + 255) / 256)      // 656

typedef unsigned short u16;
typedef unsigned int   u32;
typedef __attribute__((ext_vector_type(8))) short sfrag;   // 8 bf16 (4 VGPRs)
typedef __attribute__((ext_vector_type(4))) float f32x4;   // 4 fp32 acc

__device__ __forceinline__ u16 f2bf(float f){
  union { float f; u32 i; } v; v.f = f;
  u32 r = v.i + 0x7fffu + ((v.i >> 16) & 1u);  // RNE
  return (u16)(r >> 16);
}
__device__ __forceinline__ float bf2f(u16 u){
  union { u32 i; float f; } v; v.i = ((u32)u) << 16; return v.f;
}
__device__ __forceinline__ u32 pack2(float lo, float hi){
  return (u32)f2bf(lo) | ((u32)f2bf(hi) << 16);
}

// feat->featb bf16 (float4), (src-bucket,rel) seg histogram, dst histogram.
__global__ __launch_bounds__(256) void k_pre(const float* __restrict__ feat,
                                             u16* __restrict__ featb,
                                             const int* __restrict__ src,
                                             const int* __restrict__ et,
                                             const int* __restrict__ dst,
                                             int* __restrict__ seg_hist,
                                             int* __restrict__ hist_dst){
  int i = blockIdx.x * 256 + threadIdx.x;          // 1.6M float4 elems
  float4 f = ((const float4*)feat)[i];
  uint2 p; p.x = pack2(f.x, f.y); p.y = pack2(f.z, f.w);
  ((uint2*)featb)[i] = p;
  if (i < N_EDGES) {
    int key = (src[i] >> BSH) * N_RELS + et[i];
    atomicAdd(&seg_hist[key * 16], 1);
    atomicAdd(&hist_dst[dst[i]], 1);
  }
}

// Blocks 0..195: msgbuf slot-region allocation. Block 196: segment scan.
// Blocks 197..: weight transform: W1Tb [19][64][128] (j-major);
// W2allT [64][64]: row j=2r+o = W2[r][:,o], rows 38/39 = loop2 cols, rest 0;
// loop1Tb [64][128].
__global__ __launch_bounds__(256) void k_prep(
    const int* __restrict__ hist_dst, int* __restrict__ dstart,
    int* __restrict__ cur_dst, int* __restrict__ gcnt,
    const int* __restrict__ seg_hist, int* __restrict__ seg_off,
    int* __restrict__ cur_seg,
    const float* __restrict__ W1, const float* __restrict__ loop1,
    const float* __restrict__ W2, const float* __restrict__ loop2,
    u16* __restrict__ W1Tb, u16* __restrict__ loop1Tb,
    u16* __restrict__ W2allT){
  if (blockIdx.x >= 197) {                      // ---- weight transform ----
    int idx = (blockIdx.x - 197) * 256 + threadIdx.x;
    const int T1  = N_RELS * D_HID * D_IN;      // 155648
    const int T2c = T1 + 64 * 64;               // 159744
    const int T3  = T2c + D_HID * D_IN;         // 167936
    if (idx < T1) {
      int r = idx / (D_HID * D_IN);
      int t = idx - r * (D_HID * D_IN);
      int j = t >> 7, d = t & 127;
      W1Tb[idx] = f2bf(W1[(r * D_IN + d) * D_HID + j]);
    } else if (idx < T2c) {
      int k2 = idx - T1;
      int j = k2 >> 6, k = k2 & 63;
      float val = 0.f;
      if (j < N_RELS * D_OUT)      val = W2[((j >> 1) * D_HID + k) * D_OUT + (j & 1)];
      else if (j == 38)            val = loop2[k * 2];
      else if (j == 39)            val = loop2[k * 2 + 1];
      W2allT[k2] = f2bf(val);
    } else if (idx < T3) {
      int k2 = idx - T2c;
      int j = k2 >> 7, d = k2 & 127;
      loop1Tb[k2] = f2bf(loop1[d * D_HID + j]);
    }
    return;
  }
  if (blockIdx.x == 196) {                      // ---- segment scan ----
    __shared__ int ps[256];
    int tid = threadIdx.x;
    const int PER = (NSEG + 255) / 256;         // 8
    int lo = tid * PER, hi = lo + PER; if (hi > NSEG) hi = NSEG; if (lo > NSEG) lo = NSEG;
    int s = 0;
    for (int i = lo; i < hi; ++i) s += seg_hist[i * 16];
    ps[tid] = s;
    __syncthreads();
    if (tid == 0) { int a = 0; for (int j = 0; j < 256; ++j) { int x = ps[j]; ps[j] = a; a += x; } }
    __syncthreads();
    int eo = ps[tid];
    for (int i = lo; i < hi; ++i) {
      int c = seg_hist[i * 16];
      seg_off[i] = eo; cur_seg[i * 16] = eo;
      eo += c;
    }
    if (hi == NSEG) seg_off[NSEG] = eo;         // == N_EDGES
    return;
  }
  // ---- dst slot-region allocation ----
  __shared__ int wbase[4];
  int tid = threadIdx.x, lane = tid & 63, wv = tid >> 6;
  int n = blockIdx.x * 256 + tid;
  int v = (n < N_NODES) ? hist_dst[n] : 0;
  int x = v;
  #pragma unroll
  for (int o = 1; o < 64; o <<= 1) { int u = __shfl_up(x, o); if (lane >= o) x += u; }
  if (lane == 63) wbase[wv] = atomicAdd(gcnt, x);   // x = wave total
  __syncthreads();
  int start = wbase[wv] + x - v;
  if (n < N_NODES) { dstart[n] = start; cur_dst[n] = start; }
}

// Scatter edges into perm, grouped by (src-bucket, rel).
__global__ __launch_bounds__(256) void k_scatter(const int* __restrict__ src,
                                                 const int* __restrict__ et,
                                                 int* __restrict__ cur_seg,
                                                 int* __restrict__ perm){
  int e = blockIdx.x * 256 + threadIdx.x;
  if (e >= N_EDGES) return;
  int key = (src[e] >> BSH) * N_RELS + et[e];
  int p = atomicAdd(&cur_seg[key * 16], 1);
  perm[p] = e;
}

// Blocks < NSEG: one (src-bucket, rel) segment per block. BARRIER-FREE: each
// wave owns 32 of each 128-edge tile's rows end-to-end (slot atomic by lanes
// 0-31, pos passed to writer lanes via __shfl, msg LDS stripe wave-private).
// B-fragments read DIRECT from L2-resident W1Tb (no LDS staging) -> LDS 18.4 KB,
// 6 blocks/CU. Blocks >= NSEG: dense self-loop GEMM -> agg1b (also barrier-free,
// loop1Tb direct).
__global__ __launch_bounds__(256, 6) void k_se1(
    const u16* __restrict__ featb, const u16* __restrict__ W1Tb,
    const u16* __restrict__ loop1Tb, const float* __restrict__ b1,
    const int* __restrict__ src, const int* __restrict__ dst,
    const int* __restrict__ perm, const int* __restrict__ seg_off,
    int* __restrict__ cur_dst, int* __restrict__ srel,
    u16* __restrict__ msgbuf, u16* __restrict__ agg1b){
  __shared__ __align__(16) u16 msg[128][72];    // 18432 B; wave-private 32-row stripes
  int tid = threadIdx.x, lane = tid & 63, w4 = tid >> 6;
  int r16 = lane & 15, c4 = lane >> 4;

  if (blockIdx.x >= NSEG) {                     // ---- self-loop path ----
    int base = (blockIdx.x - NSEG) * 64;
    int arow = base + w4 * 16 + r16; if (arow >= N_NODES) arow = N_NODES - 1;
    sfrag aF[4];
    #pragma unroll
    for (int kk = 0; kk < 4; ++kk)
      aF[kk] = *(const sfrag*)(featb + (size_t)arow * D_IN + kk * 32 + c4 * 8);
    for (int ct = 0; ct < 4; ++ct) {
      int col = ct * 16 + r16;
      f32x4 acc = {0.f, 0.f, 0.f, 0.f};
      #pragma unroll
      for (int kk = 0; kk < 4; ++kk) {
        sfrag bF = *(const sfrag*)(loop1Tb + (size_t)col * D_IN + kk * 32 + c4 * 8);
        acc = __builtin_amdgcn_mfma_f32_16x16x32_bf16(aF[kk], bF, acc, 0, 0, 0);
      }
      float bias = b1[col];
      #pragma unroll
      for (int reg = 0; reg < 4; ++reg) {
        float v = acc[reg] + bias;
        float o = __shfl_xor(v, 1);
        if (!(lane & 1))
          *(u32*)&msg[w4 * 16 + c4 * 4 + reg][col] = pack2(v, o);   // wave stripe
      }
    }
    { int j = lane >> 2, q = lane & 3;          // wave-private 32B/thread flush
      int n = base + w4 * 16 + j;
      if (n < N_NODES) {
        const uint4* mr = (const uint4*)&msg[w4 * 16 + j][q * 16];
        uint4* d = (uint4*)(agg1b + (size_t)n * D_HID + q * 16);
        d[0] = mr[0]; d[1] = mr[1];
      } }
    return;
  }

  // ---- segment path ----
  const int q8 = NSEG >> 3, r8 = NSEG & 7;      // bijective XCD chunk map
  int xcd = blockIdx.x & 7, cidx = blockIdx.x >> 3;
  int seg = (xcd < r8 ? xcd * (q8 + 1) : r8 * (q8 + 1) + (xcd - r8) * q8) + cidx;
  int ts = seg_off[seg], c = seg_off[seg + 1] - ts;
  if (c == 0) return;
  int rel = seg - (seg / N_RELS) * N_RELS;      // seg % 19
  const u16* bp = W1Tb + (size_t)rel * (D_HID * D_IN);

  for (int t0 = 0; t0 < c; t0 += 128) {
    int vc = c - t0; if (vc > 128) vc = 128;
    // slot atomic: lanes 0..31 handle this wave's 32 rows
    int myPos = -1;
    if (lane < 32) {
      int row = w4 * 32 + lane;
      if (row < vc) {
        int e = perm[ts + t0 + row];
        myPos = atomicAdd(&cur_dst[dst[e]], 1);
        srel[myPos] = (src[e] << 5) | rel;
      }
    }
    // A fragments direct global->VGPR (L2-resident bucket window)
    sfrag aF[2][4];
    #pragma unroll
    for (int mt = 0; mt < 2; ++mt) {
      int row = w4 * 32 + mt * 16 + r16;
      int rr = row < vc ? row : vc - 1;
      int s = src[perm[ts + t0 + rr]];
      const u16* ap = featb + (size_t)s * D_IN + c4 * 8;
      #pragma unroll
      for (int kk = 0; kk < 4; ++kk)
        aF[mt][kk] = *(const sfrag*)(ap + kk * 32);
    }
    // MFMA; B direct from W1Tb (same addrs across waves/blocks -> L2 broadcast)
    for (int ct = 0; ct < 4; ++ct) {
      int col = ct * 16 + r16;
      sfrag bF[4];
      #pragma unroll
      for (int kk = 0; kk < 4; ++kk)
        bF[kk] = *(const sfrag*)(bp + (size_t)col * D_IN + kk * 32 + c4 * 8);
      #pragma unroll
      for (int mt = 0; mt < 2; ++mt) {
        f32x4 acc = {0.f, 0.f, 0.f, 0.f};
        #pragma unroll
        for (int kk = 0; kk < 4; ++kk)
          acc = __builtin_amdgcn_mfma_f32_16x16x32_bf16(aF[mt][kk], bF[kk], acc, 0, 0, 0);
        #pragma unroll
        for (int reg = 0; reg < 4; ++reg) {
          float v = acc[reg];
          float o = __shfl_xor(v, 1);
          if (!(lane & 1))
            *(u32*)&msg[w4 * 32 + mt * 16 + c4 * 4 + reg][col] = pack2(v, o);
        }
      }
    }
    // wave-private writeout: 2 lanes/row, pos via shuffle (no LDS posIds)
    { int j = lane >> 1, half = lane & 1;
      int pos = __shfl(myPos, j);
      if (pos >= 0) {
        const uint4* mr = (const uint4*)&msg[w4 * 32 + j][half * 32];
        uint4* d = (uint4*)(msgbuf + (size_t)pos * D_HID + half * 32);
        d[0] = mr[0]; d[1] = mr[1]; d[2] = mr[2]; d[3] = mr[3];
      } }
  }
}

// Fused: message aggregation (one node per wave, sequential msgbuf read) +
// self-loop + relu -> h1 (LDS, f32), then T2 row via 40-lane dot with W2allT:
// T2[n][2r+o] = h1[n]@W2[r][:,o]; cols 38/39 carry loop2 -> out init (+b2).
__global__ __launch_bounds__(256) void k_agg(
    const u16* __restrict__ msgbuf, const int* __restrict__ dstart,
    const int* __restrict__ cnt, const u16* __restrict__ agg1b,
    const u16* __restrict__ W2allT, const float* __restrict__ b2,
    float* __restrict__ T2f, float* __restrict__ out){
  __shared__ u16   W2ls[64][66];                // padded: bank-spread rows
  __shared__ float h1s[4][68];
  int tid = threadIdx.x, wv = tid >> 6, lane = tid & 63;
  for (int i = tid; i < 64 * 64; i += 256) W2ls[i >> 6][i & 63] = W2allT[i];
  int n = blockIdx.x * 4 + wv;
  int s = dstart[n], epos = s + cnt[n];
  int h = lane >> 5, cc = lane & 31;
  float a0 = 0.f, a1 = 0.f;
  for (int i = s + h; i < epos; i += 2) {
    u32 v = ((const u32*)msgbuf)[(size_t)i * 32 + cc];
    a0 += bf2f((u16)(v & 0xffffu));
    a1 += bf2f((u16)(v >> 16));
  }
  a0 += __shfl_down(a0, 32);
  a1 += __shfl_down(a1, 32);
  if (h == 0) {
    u32 sv = ((const u32*)agg1b)[(size_t)n * 32 + cc];
    float v0 = a0 + bf2f((u16)(sv & 0xffffu));
    float v1 = a1 + bf2f((u16)(sv >> 16));
    v0 = v0 > 0.f ? v0 : 0.f;
    v1 = v1 > 0.f ? v1 : 0.f;
    h1s[wv][2 * cc]     = v0;
    h1s[wv][2 * cc + 1] = v1;
  }
  __syncthreads();
  if (lane < 40) {
    float acc = 0.f;
    #pragma unroll 8
    for (int k = 0; k < 64; ++k)
      acc += bf2f(W2ls[lane][k]) * h1s[wv][k];
    if (lane < 38) T2f[(size_t)n * 40 + lane] = acc;
    else           out[n * 2 + (lane - 38)] = acc + b2[lane - 38];
  }
}

// Layer-2 finish: one wave per node; gather T2[src][2r..] per slot via srel,
// reduce, add to out. No global atomics.
__global__ __launch_bounds__(256) void k_fin(
    const float* __restrict__ T2f, const int* __restrict__ srel,
    const int* __restrict__ dstart, const int* __restrict__ cnt,
    float* __restrict__ out){
  int wv = threadIdx.x >> 6, lane = threadIdx.x & 63;
  int n = blockIdx.x * 4 + wv;
  int s = dstart[n], c = cnt[n];
  float ax = 0.f, ay = 0.f;
  for (int i = lane; i < c; i += 64) {
    int sr = srel[s + i];
    const float* p = T2f + (size_t)(sr >> 5) * 40 + (sr & 31) * 2;
    ax += p[0]; ay += p[1];
  }
  #pragma unroll
  for (int off = 32; off; off >>= 1) {
    ax += __shfl_down(ax, off);
    ay += __shfl_down(ay, off);
  }
  if (lane == 0) {
    out[n * 2]     += ax;
    out[n * 2 + 1] += ay;
  }
}

extern "C" void kernel_launch(void* const* d_in, const int* in_sizes, int n_in,
                              void* d_out, int out_size, void* d_ws, size_t ws_size,
                              hipStream_t stream){
  const float* feat  = (const float*)d_in[0];
  const float* W1    = (const float*)d_in[1];
  const float* loop1 = (const float*)d_in[2];
  const float* b1    = (const float*)d_in[3];
  const float* W2    = (const float*)d_in[4];
  const float* loop2 = (const float*)d_in[5];
  const float* b2    = (const float*)d_in[6];
  const int* src     = (const int*)d_in[7];
  const int* dst     = (const int*)d_in[8];
  const int* et      = (const int*)d_in[9];
  float* out = (float*)d_out;

  // workspace layout (16B-aligned), ~102 MB total.
  char* w = (char*)d_ws;
  u16*   W1Tb     = (u16*)(w);                   //  311296
  u16*   W2allT   = (u16*)(w + 311296);          //    8192 (64x64 bf16)
  u16*   loop1Tb  = (u16*)(w + 319488);          //   16384
  int*   seg_hist = (int*)(w + 335872);          //  119168 (1862 x 64B) ┐
  int*   gcnt     = (int*)(w + 455040);          //      64              ├ memset (319232 B)
  int*   hist_dst = (int*)(w + 455104);          //  200000              ┘
  int*   seg_off  = (int*)(w + 655104);          //    7488
  int*   cur_seg  = (int*)(w + 662592);          //  119168 (64B-padded)
  int*   dstart   = (int*)(w + 781760);          //  200000
  int*   cur_dst  = (int*)(w + 981760);          //  200000
  int*   perm     = (int*)(w + 1181760);         // 2400000
  int*   srel     = (int*)(w + 3581760);         // 2400000
  u16*   featb    = (u16*)(w + 5981760);         // 12.8 MB (T2f aliases; featb dead after k_se1)
  float* T2f      = (float*)(w + 5981760);       //  8.0 MB (50000 x 40 f32)
  u16*   agg1b    = (u16*)(w + 18781760);        //  6.4 MB
  u16*   msgbuf   = (u16*)(w + 25181760);        // 76.8 MB -> 101981760

  hipMemsetAsync(w + 335872, 0, 319232, stream);
  k_pre     <<<6250, 256, 0, stream>>>(feat, featb, src, et, dst, seg_hist, hist_dst);
  k_prep    <<<197 + PREP_BLOCKS, 256, 0, stream>>>(
                hist_dst, dstart, cur_dst, gcnt, seg_hist, seg_off, cur_seg,
                W1, loop1, W2, loop2, W1Tb, loop1Tb, W2allT);
  k_scatter <<<2344, 256, 0, stream>>>(src, et, cur_seg, perm);
  k_se1     <<<NSEG + SL_BLOCKS, 256, 0, stream>>>(
                featb, W1Tb, loop1Tb, b1, src, dst, perm, seg_off,
                cur_dst, srel, msgbuf, agg1b);
  k_agg     <<<12500, 256, 0, stream>>>(msgbuf, dstart, hist_dst, agg1b,
                                        W2allT, b2, T2f, out);
  k_fin     <<<12500, 256, 0, stream>>>(T2f, srel, dstart, hist_dst, out);
}

// Round 7
// 349.310 us; speedup vs baseline: 2.1975x; 1.1053x over previous
//
#include <hip/hip_runtime.h>

#define N_NODES 50000
#define N_EDGES 600000
#define N_RELS  19
#define D_IN    128
#define D_HID   64
#define D_OUT   2
#define BSH     9                                   // src bucket = 512 nodes
#define NB      ((N_NODES + 511) >> 9)              // 98
#define NSEG    (NB * N_RELS)                       // 1862
#define SL_BLOCKS ((N_NODES + 63) / 64)             // 782
#define PREP_ELEMS (N_RELS * D_HID * D_IN + 64 * 64 + D_HID * D_IN)  // 167936
#define PREP_BLOCKS ((PREP_ELEMS + 255) / 256)      // 656

typedef unsigned short u16;
typedef unsigned int   u32;
typedef __attribute__((ext_vector_type(8))) short sfrag;   // 8 bf16 (4 VGPRs)
typedef __attribute__((ext_vector_type(4))) float f32x4;   // 4 fp32 acc

__device__ __forceinline__ u16 f2bf(float f){
  union { float f; u32 i; } v; v.f = f;
  u32 r = v.i + 0x7fffu + ((v.i >> 16) & 1u);  // RNE
  return (u16)(r >> 16);
}
__device__ __forceinline__ float bf2f(u16 u){
  union { u32 i; float f; } v; v.i = ((u32)u) << 16; return v.f;
}
__device__ __forceinline__ u32 pack2(float lo, float hi){
  return (u32)f2bf(lo) | ((u32)f2bf(hi) << 16);
}

// feat->featb bf16 (float4), (src-bucket,rel) seg histogram, dst histogram.
__global__ __launch_bounds__(256) void k_pre(const float* __restrict__ feat,
                                             u16* __restrict__ featb,
                                             const int* __restrict__ src,
                                             const int* __restrict__ et,
                                             const int* __restrict__ dst,
                                             int* __restrict__ seg_hist,
                                             int* __restrict__ hist_dst){
  int i = blockIdx.x * 256 + threadIdx.x;          // 1.6M float4 elems
  float4 f = ((const float4*)feat)[i];
  uint2 p; p.x = pack2(f.x, f.y); p.y = pack2(f.z, f.w);
  ((uint2*)featb)[i] = p;
  if (i < N_EDGES) {
    int key = (src[i] >> BSH) * N_RELS + et[i];
    atomicAdd(&seg_hist[key * 16], 1);
    atomicAdd(&hist_dst[dst[i]], 1);
  }
}

// Blocks 0..195: dst slot-region allocation. Block 196: segment scan.
// Blocks 197..: weight transform: W1Tb [19][64][128] (j-major);
// W2allT [64][64]: row j=2r+o = W2[r][:,o], rows 38/39 = loop2 cols, rest 0;
// loop1Tb [64][128].
__global__ __launch_bounds__(256) void k_prep(
    const int* __restrict__ hist_dst, int* __restrict__ dstart,
    int* __restrict__ cur_dst, int* __restrict__ gcnt,
    const int* __restrict__ seg_hist, int* __restrict__ seg_off,
    int* __restrict__ cur_seg,
    const float* __restrict__ W1, const float* __restrict__ loop1,
    const float* __restrict__ W2, const float* __restrict__ loop2,
    u16* __restrict__ W1Tb, u16* __restrict__ loop1Tb,
    u16* __restrict__ W2allT){
  if (blockIdx.x >= 197) {                      // ---- weight transform ----
    int idx = (blockIdx.x - 197) * 256 + threadIdx.x;
    const int T1  = N_RELS * D_HID * D_IN;      // 155648
    const int T2c = T1 + 64 * 64;               // 159744
    const int T3  = T2c + D_HID * D_IN;         // 167936
    if (idx < T1) {
      int r = idx / (D_HID * D_IN);
      int t = idx - r * (D_HID * D_IN);
      int j = t >> 7, d = t & 127;
      W1Tb[idx] = f2bf(W1[(r * D_IN + d) * D_HID + j]);
    } else if (idx < T2c) {
      int k2 = idx - T1;
      int j = k2 >> 6, k = k2 & 63;
      float val = 0.f;
      if (j < N_RELS * D_OUT)      val = W2[((j >> 1) * D_HID + k) * D_OUT + (j & 1)];
      else if (j == 38)            val = loop2[k * 2];
      else if (j == 39)            val = loop2[k * 2 + 1];
      W2allT[k2] = f2bf(val);
    } else if (idx < T3) {
      int k2 = idx - T2c;
      int j = k2 >> 7, d = k2 & 127;
      loop1Tb[k2] = f2bf(loop1[d * D_HID + j]);
    }
    return;
  }
  if (blockIdx.x == 196) {                      // ---- segment scan ----
    __shared__ int ps[256];
    int tid = threadIdx.x;
    const int PER = (NSEG + 255) / 256;         // 8
    int lo = tid * PER, hi = lo + PER; if (hi > NSEG) hi = NSEG; if (lo > NSEG) lo = NSEG;
    int s = 0;
    for (int i = lo; i < hi; ++i) s += seg_hist[i * 16];
    ps[tid] = s;
    __syncthreads();
    if (tid == 0) { int a = 0; for (int j = 0; j < 256; ++j) { int x = ps[j]; ps[j] = a; a += x; } }
    __syncthreads();
    int eo = ps[tid];
    for (int i = lo; i < hi; ++i) {
      int c = seg_hist[i * 16];
      seg_off[i] = eo; cur_seg[i * 16] = eo;
      eo += c;
    }
    if (hi == NSEG) seg_off[NSEG] = eo;         // == N_EDGES
    return;
  }
  // ---- dst slot-region allocation ----
  __shared__ int wbase[4];
  int tid = threadIdx.x, lane = tid & 63, wv = tid >> 6;
  int n = blockIdx.x * 256 + tid;
  int v = (n < N_NODES) ? hist_dst[n] : 0;
  int x = v;
  #pragma unroll
  for (int o = 1; o < 64; o <<= 1) { int u = __shfl_up(x, o); if (lane >= o) x += u; }
  if (lane == 63) wbase[wv] = atomicAdd(gcnt, x);   // x = wave total
  __syncthreads();
  int start = wbase[wv] + x - v;
  if (n < N_NODES) { dstart[n] = start; cur_dst[n] = start; }
}

// Dual scatter: src-slot p1 (seg-grouped) gets srcid; dst-slot p2 gets
// sg2 = {(src<<5)|rel, p1} (layer-2 info + gather index). No perm array.
__global__ __launch_bounds__(256) void k_scatter(const int* __restrict__ src,
                                                 const int* __restrict__ et,
                                                 const int* __restrict__ dst,
                                                 int* __restrict__ cur_seg,
                                                 int* __restrict__ cur_dst,
                                                 int* __restrict__ srcid,
                                                 int2* __restrict__ sg2){
  int e = blockIdx.x * 256 + threadIdx.x;
  if (e >= N_EDGES) return;
  int s2 = src[e], r = et[e], d = dst[e];
  int key = (s2 >> BSH) * N_RELS + r;
  int p1 = atomicAdd(&cur_seg[key * 16], 1);
  srcid[p1] = s2;
  int p2 = atomicAdd(&cur_dst[d], 1);
  sg2[p2] = make_int2((s2 << 5) | r, p1);
}

// Blocks < NSEG: one (src-bucket, rel) segment per block. B staged ONCE in LDS
// (R3's verified scheme), A-fragments gathered direct global->VGPR via srcid
// (sequential, no indirection), msg packed in wave-private LDS stripes, and
// msgbuf written SEQUENTIALLY at slot ts+t0+row (streaming, no atomics, no
// srel). Single __syncthreads after B-stage. Blocks >= NSEG: self-loop GEMM.
__global__ __launch_bounds__(256, 4) void k_se1(
    const u16* __restrict__ featb, const u16* __restrict__ W1Tb,
    const u16* __restrict__ loop1Tb, const float* __restrict__ b1,
    const int* __restrict__ srcid, const int* __restrict__ seg_off,
    u16* __restrict__ msgbuf, u16* __restrict__ agg1b){
  __shared__ __align__(16) u16 Bls[64][136];    // 17408 B
  __shared__ __align__(16) u16 msg[128][72];    // 18432 B; wave-private stripes
  int tid = threadIdx.x, lane = tid & 63, w4 = tid >> 6;
  int r16 = lane & 15, c4 = lane >> 4;

  if (blockIdx.x >= NSEG) {                     // ---- self-loop path ----
    int base = (blockIdx.x - NSEG) * 64;
    { int j = tid >> 2, sg = tid & 3;
      const uint4* g = (const uint4*)(loop1Tb + j * 128) + sg * 4;
      uint4* d = (uint4*)&Bls[j][sg * 32];
      d[0] = g[0]; d[1] = g[1]; d[2] = g[2]; d[3] = g[3]; }
    int arow = base + w4 * 16 + r16; if (arow >= N_NODES) arow = N_NODES - 1;
    sfrag aF[4];
    #pragma unroll
    for (int kk = 0; kk < 4; ++kk)
      aF[kk] = *(const sfrag*)(featb + (size_t)arow * D_IN + kk * 32 + c4 * 8);
    __syncthreads();
    #pragma unroll
    for (int ct = 0; ct < 4; ++ct) {
      int col = ct * 16 + r16;
      f32x4 acc = {0.f, 0.f, 0.f, 0.f};
      #pragma unroll
      for (int kk = 0; kk < 4; ++kk) {
        sfrag bF = *(const sfrag*)&Bls[ct * 16 + r16][kk * 32 + c4 * 8];
        acc = __builtin_amdgcn_mfma_f32_16x16x32_bf16(aF[kk], bF, acc, 0, 0, 0);
      }
      float bias = b1[col];
      #pragma unroll
      for (int reg = 0; reg < 4; ++reg) {
        float v = acc[reg] + bias;
        float o = __shfl_xor(v, 1);
        if (!(lane & 1))
          *(u32*)&msg[w4 * 16 + c4 * 4 + reg][col] = pack2(v, o);   // wave stripe
      }
    }
    { int j = lane >> 2, q = lane & 3;          // wave-private 32B/thread flush
      int n = base + w4 * 16 + j;
      if (n < N_NODES) {
        const uint4* mr = (const uint4*)&msg[w4 * 16 + j][q * 16];
        uint4* d = (uint4*)(agg1b + (size_t)n * D_HID + q * 16);
        d[0] = mr[0]; d[1] = mr[1];
      } }
    return;
  }

  // ---- segment path ----
  const int q8 = NSEG >> 3, r8 = NSEG & 7;      // bijective XCD chunk map
  int xcd = blockIdx.x & 7, cidx = blockIdx.x >> 3;
  int seg = (xcd < r8 ? xcd * (q8 + 1) : r8 * (q8 + 1) + (xcd - r8) * q8) + cidx;
  int ts = seg_off[seg], c = seg_off[seg + 1] - ts;
  if (c == 0) return;
  int rel = seg - (seg / N_RELS) * N_RELS;      // seg % 19

  { // B tile: W1Tb[rel], 64 x 128 bf16, staged ONCE per segment
    int j = tid >> 2, sg = tid & 3;
    const uint4* g = (const uint4*)(W1Tb + ((size_t)rel * 64 + j) * 128) + sg * 4;
    uint4* d = (uint4*)&Bls[j][sg * 32];
    d[0] = g[0]; d[1] = g[1]; d[2] = g[2]; d[3] = g[3];
  }
  __syncthreads();                              // only barrier in the kernel

  for (int t0 = 0; t0 < c; t0 += 128) {
    int vc = c - t0; if (vc > 128) vc = 128;
    // A fragments direct global->VGPR (srcid sequential; featb L2-bucket-local)
    sfrag aF[2][4];
    #pragma unroll
    for (int mt = 0; mt < 2; ++mt) {
      int row = w4 * 32 + mt * 16 + r16;
      int rr = row < vc ? row : vc - 1;
      int s = srcid[ts + t0 + rr];
      const u16* ap = featb + (size_t)s * D_IN + c4 * 8;
      #pragma unroll
      for (int kk = 0; kk < 4; ++kk)
        aF[mt][kk] = *(const sfrag*)(ap + kk * 32);
    }
    #pragma unroll
    for (int ct = 0; ct < 4; ++ct) {
      int col = ct * 16 + r16;
      sfrag bF[4];
      #pragma unroll
      for (int kk = 0; kk < 4; ++kk)
        bF[kk] = *(const sfrag*)&Bls[ct * 16 + r16][kk * 32 + c4 * 8];
      #pragma unroll
      for (int mt = 0; mt < 2; ++mt) {
        f32x4 acc = {0.f, 0.f, 0.f, 0.f};
        #pragma unroll
        for (int kk = 0; kk < 4; ++kk)
          acc = __builtin_amdgcn_mfma_f32_16x16x32_bf16(aF[mt][kk], bF[kk], acc, 0, 0, 0);
        #pragma unroll
        for (int reg = 0; reg < 4; ++reg) {
          float v = acc[reg];
          float o = __shfl_xor(v, 1);
          if (!(lane & 1))
            *(u32*)&msg[w4 * 32 + mt * 16 + c4 * 4 + reg][col] = pack2(v, o);
        }
      }
    }
    // SEQUENTIAL writeout: slot = ts+t0+row (streaming, coalesced, wave-private)
    { int j = lane >> 1, half = lane & 1;
      int row = w4 * 32 + j;
      if (row < vc) {
        const uint4* mr = (const uint4*)&msg[row][half * 32];
        uint4* d = (uint4*)(msgbuf + (size_t)(ts + t0 + row) * D_HID + half * 32);
        d[0] = mr[0]; d[1] = mr[1]; d[2] = mr[2]; d[3] = mr[3];
      } }
  }
}

// Fused: message aggregation (one node per wave, GATHER msgbuf rows via
// sg2[i].y) + self-loop + relu -> h1 (LDS f32), then T2 row via 40-lane dot:
// T2[n][2r+o] = h1[n]@W2[r][:,o]; cols 38/39 carry loop2 -> out init (+b2).
__global__ __launch_bounds__(256) void k_agg(
    const u16* __restrict__ msgbuf, const int2* __restrict__ sg2,
    const int* __restrict__ dstart, const int* __restrict__ cnt,
    const u16* __restrict__ agg1b, const u16* __restrict__ W2allT,
    const float* __restrict__ b2, float* __restrict__ T2f,
    float* __restrict__ out){
  __shared__ u16   W2ls[64][66];                // padded: bank-spread rows
  __shared__ float h1s[4][68];
  int tid = threadIdx.x, wv = tid >> 6, lane = tid & 63;
  for (int i = tid; i < 64 * 64; i += 256) W2ls[i >> 6][i & 63] = W2allT[i];
  int n = blockIdx.x * 4 + wv;
  int s = dstart[n], epos = s + cnt[n];
  int h = lane >> 5, cc = lane & 31;
  float a0 = 0.f, a1 = 0.f;
  for (int i = s + h; i < epos; i += 2) {
    int j = sg2[i].y;                           // src-order slot (gather index)
    u32 v = ((const u32*)msgbuf)[(size_t)j * 32 + cc];
    a0 += bf2f((u16)(v & 0xffffu));
    a1 += bf2f((u16)(v >> 16));
  }
  a0 += __shfl_down(a0, 32);
  a1 += __shfl_down(a1, 32);
  if (h == 0) {
    u32 sv = ((const u32*)agg1b)[(size_t)n * 32 + cc];
    float v0 = a0 + bf2f((u16)(sv & 0xffffu));
    float v1 = a1 + bf2f((u16)(sv >> 16));
    v0 = v0 > 0.f ? v0 : 0.f;
    v1 = v1 > 0.f ? v1 : 0.f;
    h1s[wv][2 * cc]     = v0;
    h1s[wv][2 * cc + 1] = v1;
  }
  __syncthreads();
  if (lane < 40) {
    float acc = 0.f;
    #pragma unroll 8
    for (int k = 0; k < 64; ++k)
      acc += bf2f(W2ls[lane][k]) * h1s[wv][k];
    if (lane < 38) T2f[(size_t)n * 40 + lane] = acc;
    else           out[n * 2 + (lane - 38)] = acc + b2[lane - 38];
  }
}

// Layer-2 finish: one wave per node; gather T2[src][2r..] per slot via sg2.x,
// reduce, add to out. No global atomics.
__global__ __launch_bounds__(256) void k_fin(
    const float* __restrict__ T2f, const int2* __restrict__ sg2,
    const int* __restrict__ dstart, const int* __restrict__ cnt,
    float* __restrict__ out){
  int wv = threadIdx.x >> 6, lane = threadIdx.x & 63;
  int n = blockIdx.x * 4 + wv;
  int s = dstart[n], c = cnt[n];
  float ax = 0.f, ay = 0.f;
  for (int i = lane; i < c; i += 64) {
    int sr = sg2[s + i].x;
    const float* p = T2f + (size_t)(sr >> 5) * 40 + (sr & 31) * 2;
    ax += p[0]; ay += p[1];
  }
  #pragma unroll
  for (int off = 32; off; off >>= 1) {
    ax += __shfl_down(ax, off);
    ay += __shfl_down(ay, off);
  }
  if (lane == 0) {
    out[n * 2]     += ax;
    out[n * 2 + 1] += ay;
  }
}

extern "C" void kernel_launch(void* const* d_in, const int* in_sizes, int n_in,
                              void* d_out, int out_size, void* d_ws, size_t ws_size,
                              hipStream_t stream){
  const float* feat  = (const float*)d_in[0];
  const float* W1    = (const float*)d_in[1];
  const float* loop1 = (const float*)d_in[2];
  const float* b1    = (const float*)d_in[3];
  const float* W2    = (const float*)d_in[4];
  const float* loop2 = (const float*)d_in[5];
  const float* b2    = (const float*)d_in[6];
  const int* src     = (const int*)d_in[7];
  const int* dst     = (const int*)d_in[8];
  const int* et      = (const int*)d_in[9];
  float* out = (float*)d_out;

  // workspace layout (16B-aligned), ~104.4 MB total.
  char* w = (char*)d_ws;
  u16*   W1Tb     = (u16*)(w);                   //  311296
  u16*   W2allT   = (u16*)(w + 311296);          //    8192 (64x64 bf16)
  u16*   loop1Tb  = (u16*)(w + 319488);          //   16384
  int*   seg_hist = (int*)(w + 335872);          //  119168 (1862 x 64B) ┐
  int*   gcnt     = (int*)(w + 455040);          //      64              ├ memset (319232 B)
  int*   hist_dst = (int*)(w + 455104);          //  200000              ┘
  int*   seg_off  = (int*)(w + 655104);          //    7488
  int*   cur_seg  = (int*)(w + 662592);          //  119168 (64B-padded)
  int*   dstart   = (int*)(w + 781760);          //  200000
  int*   cur_dst  = (int*)(w + 981760);          //  200000
  int*   srcid    = (int*)(w + 1181760);         // 2400000
  int2*  sg2      = (int2*)(w + 3581760);        // 4800000
  u16*   featb    = (u16*)(w + 8381760);         // 12.8 MB (T2f aliases; featb dead after k_se1)
  float* T2f      = (float*)(w + 8381760);       //  8.0 MB (50000 x 40 f32)
  u16*   agg1b    = (u16*)(w + 21181760);        //  6.4 MB
  u16*   msgbuf   = (u16*)(w + 27581760);        // 76.8 MB -> 104381760

  hipMemsetAsync(w + 335872, 0, 319232, stream);
  k_pre     <<<6250, 256, 0, stream>>>(feat, featb, src, et, dst, seg_hist, hist_dst);
  k_prep    <<<197 + PREP_BLOCKS, 256, 0, stream>>>(
                hist_dst, dstart, cur_dst, gcnt, seg_hist, seg_off, cur_seg,
                W1, loop1, W2, loop2, W1Tb, loop1Tb, W2allT);
  k_scatter <<<2344, 256, 0, stream>>>(src, et, dst, cur_seg, cur_dst, srcid, sg2);
  k_se1     <<<NSEG + SL_BLOCKS, 256, 0, stream>>>(
                featb, W1Tb, loop1Tb, b1, srcid, seg_off, msgbuf, agg1b);
  k_agg     <<<12500, 256, 0, stream>>>(msgbuf, sg2, dstart, hist_dst, agg1b,
                                        W2allT, b2, T2f, out);
  k_fin     <<<12500, 256, 0, stream>>>(T2f, sg2, dstart, hist_dst, out);
}

// Round 8
// 312.194 us; speedup vs baseline: 2.4587x; 1.1189x over previous
//
#include <hip/hip_runtime.h>

#define N_NODES 50000
#define N_EDGES 600000
#define N_RELS  19
#define D_IN    128
#define D_HID   64
#define D_OUT   2
#define BSH     9                                   // src bucket = 512 nodes
#define NB      ((N_NODES + 511) >> 9)              // 98
#define NSEG    (NB * N_RELS)                       // 1862
#define SL_BLOCKS ((N_NODES + 63) / 64)             // 782
#define PREP_ELEMS (N_RELS * D_HID * D_IN + 64 * 64 + D_HID * D_IN)  // 167936
#define PREP_BLOCKS ((PREP_ELEMS + 255) / 256)      // 656

typedef unsigned short u16;
typedef unsigned int   u32;
typedef __attribute__((ext_vector_type(8))) short sfrag;   // 8 bf16 (4 VGPRs)
typedef __attribute__((ext_vector_type(4))) float f32x4;   // 4 fp32 acc

__device__ __forceinline__ u16 f2bf(float f){
  union { float f; u32 i; } v; v.f = f;
  u32 r = v.i + 0x7fffu + ((v.i >> 16) & 1u);  // RNE
  return (u16)(r >> 16);
}
__device__ __forceinline__ float bf2f(u16 u){
  union { u32 i; float f; } v; v.i = ((u32)u) << 16; return v.f;
}
__device__ __forceinline__ u32 pack2(float lo, float hi){
  return (u32)f2bf(lo) | ((u32)f2bf(hi) << 16);
}

// feat->featb bf16 (float4), (src-bucket,rel) seg histogram, dst histogram.
__global__ __launch_bounds__(256) void k_pre(const float* __restrict__ feat,
                                             u16* __restrict__ featb,
                                             const int* __restrict__ src,
                                             const int* __restrict__ et,
                                             const int* __restrict__ dst,
                                             int* __restrict__ seg_hist,
                                             int* __restrict__ hist_dst){
  int i = blockIdx.x * 256 + threadIdx.x;          // 1.6M float4 elems
  float4 f = ((const float4*)feat)[i];
  uint2 p; p.x = pack2(f.x, f.y); p.y = pack2(f.z, f.w);
  ((uint2*)featb)[i] = p;
  if (i < N_EDGES) {
    int key = (src[i] >> BSH) * N_RELS + et[i];
    atomicAdd(&seg_hist[key * 16], 1);
    atomicAdd(&hist_dst[dst[i]], 1);
  }
}

// Blocks 0..195: dst slot-region allocation. Block 196: segment scan.
// Blocks 197..: weight transform: W1Tb [19][64][128] (j-major);
// W2allT [64][64]: row j=2r+o = W2[r][:,o], rows 38/39 = loop2 cols, rest 0;
// loop1Tb [64][128].
__global__ __launch_bounds__(256) void k_prep(
    const int* __restrict__ hist_dst, int* __restrict__ dstart,
    int* __restrict__ cur_dst, int* __restrict__ gcnt,
    const int* __restrict__ seg_hist, int* __restrict__ seg_off,
    int* __restrict__ cur_seg,
    const float* __restrict__ W1, const float* __restrict__ loop1,
    const float* __restrict__ W2, const float* __restrict__ loop2,
    u16* __restrict__ W1Tb, u16* __restrict__ loop1Tb,
    u16* __restrict__ W2allT){
  if (blockIdx.x >= 197) {                      // ---- weight transform ----
    int idx = (blockIdx.x - 197) * 256 + threadIdx.x;
    const int T1  = N_RELS * D_HID * D_IN;      // 155648
    const int T2c = T1 + 64 * 64;               // 159744
    const int T3  = T2c + D_HID * D_IN;         // 167936
    if (idx < T1) {
      int r = idx / (D_HID * D_IN);
      int t = idx - r * (D_HID * D_IN);
      int j = t >> 7, d = t & 127;
      W1Tb[idx] = f2bf(W1[(r * D_IN + d) * D_HID + j]);
    } else if (idx < T2c) {
      int k2 = idx - T1;
      int j = k2 >> 6, k = k2 & 63;
      float val = 0.f;
      if (j < N_RELS * D_OUT)      val = W2[((j >> 1) * D_HID + k) * D_OUT + (j & 1)];
      else if (j == 38)            val = loop2[k * 2];
      else if (j == 39)            val = loop2[k * 2 + 1];
      W2allT[k2] = f2bf(val);
    } else if (idx < T3) {
      int k2 = idx - T2c;
      int j = k2 >> 7, d = k2 & 127;
      loop1Tb[k2] = f2bf(loop1[d * D_HID + j]);
    }
    return;
  }
  if (blockIdx.x == 196) {                      // ---- segment scan ----
    __shared__ int ps[256];
    int tid = threadIdx.x;
    const int PER = (NSEG + 255) / 256;         // 8
    int lo = tid * PER, hi = lo + PER; if (hi > NSEG) hi = NSEG; if (lo > NSEG) lo = NSEG;
    int s = 0;
    for (int i = lo; i < hi; ++i) s += seg_hist[i * 16];
    ps[tid] = s;
    __syncthreads();
    if (tid == 0) { int a = 0; for (int j = 0; j < 256; ++j) { int x = ps[j]; ps[j] = a; a += x; } }
    __syncthreads();
    int eo = ps[tid];
    for (int i = lo; i < hi; ++i) {
      int c = seg_hist[i * 16];
      seg_off[i] = eo; cur_seg[i * 16] = eo;
      eo += c;
    }
    if (hi == NSEG) seg_off[NSEG] = eo;         // == N_EDGES
    return;
  }
  // ---- dst slot-region allocation ----
  __shared__ int wbase[4];
  int tid = threadIdx.x, lane = tid & 63, wv = tid >> 6;
  int n = blockIdx.x * 256 + tid;
  int v = (n < N_NODES) ? hist_dst[n] : 0;
  int x = v;
  #pragma unroll
  for (int o = 1; o < 64; o <<= 1) { int u = __shfl_up(x, o); if (lane >= o) x += u; }
  if (lane == 63) wbase[wv] = atomicAdd(gcnt, x);   // x = wave total
  __syncthreads();
  int start = wbase[wv] + x - v;
  if (n < N_NODES) { dstart[n] = start; cur_dst[n] = start; }
}

// Scatter edges into perm, grouped by (src-bucket, rel). One atomic, 4B write.
__global__ __launch_bounds__(256) void k_scatter(const int* __restrict__ src,
                                                 const int* __restrict__ et,
                                                 int* __restrict__ cur_seg,
                                                 int* __restrict__ perm){
  int e = blockIdx.x * 256 + threadIdx.x;
  if (e >= N_EDGES) return;
  int key = (src[e] >> BSH) * N_RELS + et[e];
  int p = atomicAdd(&cur_seg[key * 16], 1);
  perm[p] = e;
}

// Blocks < NSEG: one (src-bucket, rel) segment per block. B staged ONCE in LDS
// (R3's traffic-optimal scheme); inner tile loop is BARRIER-FREE (R6's verified
// pattern): lanes 0-31 of each wave own rows w4*32+lane end-to-end (slot atomic
// + srel write), pos handed to writer lanes via __shfl, msg LDS stripes
// wave-private. Single __syncthreads after B-stage.
// Blocks >= NSEG: dense self-loop GEMM -> agg1b.
__global__ __launch_bounds__(256, 4) void k_se1(
    const u16* __restrict__ featb, const u16* __restrict__ W1Tb,
    const u16* __restrict__ loop1Tb, const float* __restrict__ b1,
    const int* __restrict__ src, const int* __restrict__ dst,
    const int* __restrict__ perm, const int* __restrict__ seg_off,
    int* __restrict__ cur_dst, int* __restrict__ srel,
    u16* __restrict__ msgbuf, u16* __restrict__ agg1b){
  __shared__ __align__(16) u16 Bls[64][136];    // 17408 B
  __shared__ __align__(16) u16 msg[128][72];    // 18432 B; wave-private stripes
  int tid = threadIdx.x, lane = tid & 63, w4 = tid >> 6;
  int r16 = lane & 15, c4 = lane >> 4;

  if (blockIdx.x >= NSEG) {                     // ---- self-loop path ----
    int base = (blockIdx.x - NSEG) * 64;
    { int j = tid >> 2, sg = tid & 3;
      const uint4* g = (const uint4*)(loop1Tb + j * 128) + sg * 4;
      uint4* d = (uint4*)&Bls[j][sg * 32];
      d[0] = g[0]; d[1] = g[1]; d[2] = g[2]; d[3] = g[3]; }
    int arow = base + w4 * 16 + r16; if (arow >= N_NODES) arow = N_NODES - 1;
    sfrag aF[4];
    #pragma unroll
    for (int kk = 0; kk < 4; ++kk)
      aF[kk] = *(const sfrag*)(featb + (size_t)arow * D_IN + kk * 32 + c4 * 8);
    __syncthreads();
    #pragma unroll
    for (int ct = 0; ct < 4; ++ct) {
      int col = ct * 16 + r16;
      f32x4 acc = {0.f, 0.f, 0.f, 0.f};
      #pragma unroll
      for (int kk = 0; kk < 4; ++kk) {
        sfrag bF = *(const sfrag*)&Bls[ct * 16 + r16][kk * 32 + c4 * 8];
        acc = __builtin_amdgcn_mfma_f32_16x16x32_bf16(aF[kk], bF, acc, 0, 0, 0);
      }
      float bias = b1[col];
      #pragma unroll
      for (int reg = 0; reg < 4; ++reg) {
        float v = acc[reg] + bias;
        float o = __shfl_xor(v, 1);
        if (!(lane & 1))
          *(u32*)&msg[w4 * 16 + c4 * 4 + reg][col] = pack2(v, o);   // wave stripe
      }
    }
    { int j = lane >> 2, q = lane & 3;          // wave-private 32B/thread flush
      int n = base + w4 * 16 + j;
      if (n < N_NODES) {
        const uint4* mr = (const uint4*)&msg[w4 * 16 + j][q * 16];
        uint4* d = (uint4*)(agg1b + (size_t)n * D_HID + q * 16);
        d[0] = mr[0]; d[1] = mr[1];
      } }
    return;
  }

  // ---- segment path ----
  const int q8 = NSEG >> 3, r8 = NSEG & 7;      // bijective XCD chunk map
  int xcd = blockIdx.x & 7, cidx = blockIdx.x >> 3;
  int seg = (xcd < r8 ? xcd * (q8 + 1) : r8 * (q8 + 1) + (xcd - r8) * q8) + cidx;
  int ts = seg_off[seg], c = seg_off[seg + 1] - ts;
  if (c == 0) return;
  int rel = seg - (seg / N_RELS) * N_RELS;      // seg % 19

  { // B tile: W1Tb[rel], 64 x 128 bf16, staged ONCE per segment
    int j = tid >> 2, sg = tid & 3;
    const uint4* g = (const uint4*)(W1Tb + ((size_t)rel * 64 + j) * 128) + sg * 4;
    uint4* d = (uint4*)&Bls[j][sg * 32];
    d[0] = g[0]; d[1] = g[1]; d[2] = g[2]; d[3] = g[3];
  }
  __syncthreads();                              // only barrier in the kernel

  for (int t0 = 0; t0 < c; t0 += 128) {
    int vc = c - t0; if (vc > 128) vc = 128;
    // slot atomic + srel: lanes 0..31 own this wave's 32 rows
    int myPos = -1;
    if (lane < 32) {
      int row = w4 * 32 + lane;
      if (row < vc) {
        int e = perm[ts + t0 + row];
        myPos = atomicAdd(&cur_dst[dst[e]], 1);
        srel[myPos] = (src[e] << 5) | rel;
      }
    }
    // A fragments direct global->VGPR (featb L2-bucket-local)
    sfrag aF[2][4];
    #pragma unroll
    for (int mt = 0; mt < 2; ++mt) {
      int row = w4 * 32 + mt * 16 + r16;
      int rr = row < vc ? row : vc - 1;
      int s = src[perm[ts + t0 + rr]];
      const u16* ap = featb + (size_t)s * D_IN + c4 * 8;
      #pragma unroll
      for (int kk = 0; kk < 4; ++kk)
        aF[mt][kk] = *(const sfrag*)(ap + kk * 32);
    }
    #pragma unroll
    for (int ct = 0; ct < 4; ++ct) {
      int col = ct * 16 + r16;
      sfrag bF[4];
      #pragma unroll
      for (int kk = 0; kk < 4; ++kk)
        bF[kk] = *(const sfrag*)&Bls[ct * 16 + r16][kk * 32 + c4 * 8];
      #pragma unroll
      for (int mt = 0; mt < 2; ++mt) {
        f32x4 acc = {0.f, 0.f, 0.f, 0.f};
        #pragma unroll
        for (int kk = 0; kk < 4; ++kk)
          acc = __builtin_amdgcn_mfma_f32_16x16x32_bf16(aF[mt][kk], bF[kk], acc, 0, 0, 0);
        #pragma unroll
        for (int reg = 0; reg < 4; ++reg) {
          float v = acc[reg];
          float o = __shfl_xor(v, 1);
          if (!(lane & 1))
            *(u32*)&msg[w4 * 32 + mt * 16 + c4 * 4 + reg][col] = pack2(v, o);
        }
      }
    }
    // wave-private writeout: 2 lanes/row, pos via shuffle (no barriers)
    { int j = lane >> 1, half = lane & 1;
      int pos = __shfl(myPos, j);
      if (pos >= 0) {
        const uint4* mr = (const uint4*)&msg[w4 * 32 + j][half * 32];
        uint4* d = (uint4*)(msgbuf + (size_t)pos * D_HID + half * 32);
        d[0] = mr[0]; d[1] = mr[1]; d[2] = mr[2]; d[3] = mr[3];
      } }
  }
}

// Fused: message aggregation (one node per wave, sequential msgbuf read) +
// self-loop + relu -> h1 (LDS f32, wave-private), then T2 row via 40-lane dot:
// T2[n][2r+o] = h1[n]@W2[r][:,o]; cols 38/39 carry loop2 -> out init (+b2).
__global__ __launch_bounds__(256) void k_agg(
    const u16* __restrict__ msgbuf, const int* __restrict__ dstart,
    const int* __restrict__ cnt, const u16* __restrict__ agg1b,
    const u16* __restrict__ W2allT, const float* __restrict__ b2,
    float* __restrict__ T2f, float* __restrict__ out){
  __shared__ u16   W2ls[64][66];                // padded: bank-spread rows
  __shared__ float h1s[4][68];
  int tid = threadIdx.x, wv = tid >> 6, lane = tid & 63;
  for (int i = tid; i < 64 * 64; i += 256) W2ls[i >> 6][i & 63] = W2allT[i];
  int n = blockIdx.x * 4 + wv;
  int s = dstart[n], epos = s + cnt[n];
  int h = lane >> 5, cc = lane & 31;
  float a0 = 0.f, a1 = 0.f;
  for (int i = s + h; i < epos; i += 2) {
    u32 v = ((const u32*)msgbuf)[(size_t)i * 32 + cc];
    a0 += bf2f((u16)(v & 0xffffu));
    a1 += bf2f((u16)(v >> 16));
  }
  a0 += __shfl_down(a0, 32);
  a1 += __shfl_down(a1, 32);
  if (h == 0) {
    u32 sv = ((const u32*)agg1b)[(size_t)n * 32 + cc];
    float v0 = a0 + bf2f((u16)(sv & 0xffffu));
    float v1 = a1 + bf2f((u16)(sv >> 16));
    v0 = v0 > 0.f ? v0 : 0.f;
    v1 = v1 > 0.f ? v1 : 0.f;
    h1s[wv][2 * cc]     = v0;
    h1s[wv][2 * cc + 1] = v1;
  }
  __syncthreads();                              // W2ls visible (h1s wave-private)
  if (lane < 40) {
    float acc = 0.f;
    #pragma unroll 8
    for (int k = 0; k < 64; ++k)
      acc += bf2f(W2ls[lane][k]) * h1s[wv][k];
    if (lane < 38) T2f[(size_t)n * 40 + lane] = acc;
    else           out[n * 2 + (lane - 38)] = acc + b2[lane - 38];
  }
}

// Layer-2 finish: one wave per node; sequential srel read, 8B T2 gather per
// slot, reduce, add to out. No global atomics.
__global__ __launch_bounds__(256) void k_fin(
    const float* __restrict__ T2f, const int* __restrict__ srel,
    const int* __restrict__ dstart, const int* __restrict__ cnt,
    float* __restrict__ out){
  int wv = threadIdx.x >> 6, lane = threadIdx.x & 63;
  int n = blockIdx.x * 4 + wv;
  int s = dstart[n], c = cnt[n];
  float ax = 0.f, ay = 0.f;
  for (int i = lane; i < c; i += 64) {
    int sr = srel[s + i];
    const float* p = T2f + (size_t)(sr >> 5) * 40 + (sr & 31) * 2;
    ax += p[0]; ay += p[1];
  }
  #pragma unroll
  for (int off = 32; off; off >>= 1) {
    ax += __shfl_down(ax, off);
    ay += __shfl_down(ay, off);
  }
  if (lane == 0) {
    out[n * 2]     += ax;
    out[n * 2 + 1] += ay;
  }
}

extern "C" void kernel_launch(void* const* d_in, const int* in_sizes, int n_in,
                              void* d_out, int out_size, void* d_ws, size_t ws_size,
                              hipStream_t stream){
  const float* feat  = (const float*)d_in[0];
  const float* W1    = (const float*)d_in[1];
  const float* loop1 = (const float*)d_in[2];
  const float* b1    = (const float*)d_in[3];
  const float* W2    = (const float*)d_in[4];
  const float* loop2 = (const float*)d_in[5];
  const float* b2    = (const float*)d_in[6];
  const int* src     = (const int*)d_in[7];
  const int* dst     = (const int*)d_in[8];
  const int* et      = (const int*)d_in[9];
  float* out = (float*)d_out;

  // workspace layout (16B-aligned), ~102 MB total.
  char* w = (char*)d_ws;
  u16*   W1Tb     = (u16*)(w);                   //  311296
  u16*   W2allT   = (u16*)(w + 311296);          //    8192 (64x64 bf16)
  u16*   loop1Tb  = (u16*)(w + 319488);          //   16384
  int*   seg_hist = (int*)(w + 335872);          //  119168 (1862 x 64B) ┐
  int*   gcnt     = (int*)(w + 455040);          //      64              ├ memset (319232 B)
  int*   hist_dst = (int*)(w + 455104);          //  200000              ┘
  int*   seg_off  = (int*)(w + 655104);          //    7488
  int*   cur_seg  = (int*)(w + 662592);          //  119168 (64B-padded)
  int*   dstart   = (int*)(w + 781760);          //  200000
  int*   cur_dst  = (int*)(w + 981760);          //  200000
  int*   perm     = (int*)(w + 1181760);         // 2400000
  int*   srel     = (int*)(w + 3581760);         // 2400000
  u16*   featb    = (u16*)(w + 5981760);         // 12.8 MB (T2f aliases; featb dead after k_se1)
  float* T2f      = (float*)(w + 5981760);       //  8.0 MB (50000 x 40 f32)
  u16*   agg1b    = (u16*)(w + 18781760);        //  6.4 MB
  u16*   msgbuf   = (u16*)(w + 25181760);        // 76.8 MB -> 101981760

  hipMemsetAsync(w + 335872, 0, 319232, stream);
  k_pre     <<<6250, 256, 0, stream>>>(feat, featb, src, et, dst, seg_hist, hist_dst);
  k_prep    <<<197 + PREP_BLOCKS, 256, 0, stream>>>(
                hist_dst, dstart, cur_dst, gcnt, seg_hist, seg_off, cur_seg,
                W1, loop1, W2, loop2, W1Tb, loop1Tb, W2allT);
  k_scatter <<<2344, 256, 0, stream>>>(src, et, cur_seg, perm);
  k_se1     <<<NSEG + SL_BLOCKS, 256, 0, stream>>>(
                featb, W1Tb, loop1Tb, b1, src, dst, perm, seg_off,
                cur_dst, srel, msgbuf, agg1b);
  k_agg     <<<12500, 256, 0, stream>>>(msgbuf, dstart, hist_dst, agg1b,
                                        W2allT, b2, T2f, out);
  k_fin     <<<12500, 256, 0, stream>>>(T2f, srel, dstart, hist_dst, out);
}

// Round 10
// 311.233 us; speedup vs baseline: 2.4663x; 1.0031x over previous
//
#include <hip/hip_runtime.h>

#define N_NODES 50000
#define N_EDGES 600000
#define N_RELS  19
#define D_IN    128
#define D_HID   64
#define D_OUT   2
#define BSH     9                                   // src bucket = 512 nodes
#define NB      ((N_NODES + 511) >> 9)              // 98
#define NSEG    (NB * N_RELS)                       // 1862
#define SL_BLOCKS ((N_NODES + 63) / 64)             // 782
#define PREP_ELEMS (N_RELS * D_HID * D_IN + 64 * 64 + D_HID * D_IN)  // 167936
#define PREP_BLOCKS ((PREP_ELEMS + 255) / 256)      // 656

typedef unsigned short u16;
typedef unsigned int   u32;
typedef __attribute__((ext_vector_type(8))) short sfrag;   // 8 bf16 (4 VGPRs)
typedef __attribute__((ext_vector_type(4))) float f32x4;   // 4 fp32 acc

__device__ __forceinline__ u16 f2bf(float f){
  union { float f; u32 i; } v; v.f = f;
  u32 r = v.i + 0x7fffu + ((v.i >> 16) & 1u);  // RNE
  return (u16)(r >> 16);
}
__device__ __forceinline__ float bf2f(u16 u){
  union { u32 i; float f; } v; v.i = ((u32)u) << 16; return v.f;
}
__device__ __forceinline__ u32 pack2(float lo, float hi){
  return (u32)f2bf(lo) | ((u32)f2bf(hi) << 16);
}

// feat->featb bf16 (float4), (src-bucket,rel) seg histogram, dst histogram.
__global__ __launch_bounds__(256) void k_pre(const float* __restrict__ feat,
                                             u16* __restrict__ featb,
                                             const int* __restrict__ src,
                                             const int* __restrict__ et,
                                             const int* __restrict__ dst,
                                             int* __restrict__ seg_hist,
                                             int* __restrict__ hist_dst){
  int i = blockIdx.x * 256 + threadIdx.x;          // 1.6M float4 elems
  float4 f = ((const float4*)feat)[i];
  uint2 p; p.x = pack2(f.x, f.y); p.y = pack2(f.z, f.w);
  ((uint2*)featb)[i] = p;
  if (i < N_EDGES) {
    int key = (src[i] >> BSH) * N_RELS + et[i];
    atomicAdd(&seg_hist[key * 16], 1);
    atomicAdd(&hist_dst[dst[i]], 1);
  }
}

// Blocks 0..195: dst slot-region allocation. Block 196: segment scan.
// Blocks 197..: weight transform: W1Tb [19][64][128] (j-major);
// W2allT [64][64]: row j=2r+o = W2[r][:,o], rows 38/39 = loop2 cols, rest 0;
// loop1Tb [64][128].
__global__ __launch_bounds__(256) void k_prep(
    const int* __restrict__ hist_dst, int* __restrict__ dstart,
    int* __restrict__ cur_dst, int* __restrict__ gcnt,
    const int* __restrict__ seg_hist, int* __restrict__ seg_off,
    int* __restrict__ cur_seg,
    const float* __restrict__ W1, const float* __restrict__ loop1,
    const float* __restrict__ W2, const float* __restrict__ loop2,
    u16* __restrict__ W1Tb, u16* __restrict__ loop1Tb,
    u16* __restrict__ W2allT){
  if (blockIdx.x >= 197) {                      // ---- weight transform ----
    int idx = (blockIdx.x - 197) * 256 + threadIdx.x;
    const int T1  = N_RELS * D_HID * D_IN;      // 155648
    const int T2c = T1 + 64 * 64;               // 159744
    const int T3  = T2c + D_HID * D_IN;         // 167936
    if (idx < T1) {
      int r = idx / (D_HID * D_IN);
      int t = idx - r * (D_HID * D_IN);
      int j = t >> 7, d = t & 127;
      W1Tb[idx] = f2bf(W1[(r * D_IN + d) * D_HID + j]);
    } else if (idx < T2c) {
      int k2 = idx - T1;
      int j = k2 >> 6, k = k2 & 63;
      float val = 0.f;
      if (j < N_RELS * D_OUT)      val = W2[((j >> 1) * D_HID + k) * D_OUT + (j & 1)];
      else if (j == 38)            val = loop2[k * 2];
      else if (j == 39)            val = loop2[k * 2 + 1];
      W2allT[k2] = f2bf(val);
    } else if (idx < T3) {
      int k2 = idx - T2c;
      int j = k2 >> 7, d = k2 & 127;
      loop1Tb[k2] = f2bf(loop1[d * D_HID + j]);
    }
    return;
  }
  if (blockIdx.x == 196) {                      // ---- segment scan ----
    __shared__ int ps[256];
    int tid = threadIdx.x;
    const int PER = (NSEG + 255) / 256;         // 8
    int lo = tid * PER, hi = lo + PER; if (hi > NSEG) hi = NSEG; if (lo > NSEG) lo = NSEG;
    int s = 0;
    for (int i = lo; i < hi; ++i) s += seg_hist[i * 16];
    ps[tid] = s;
    __syncthreads();
    if (tid == 0) { int a = 0; for (int j = 0; j < 256; ++j) { int x = ps[j]; ps[j] = a; a += x; } }
    __syncthreads();
    int eo = ps[tid];
    for (int i = lo; i < hi; ++i) {
      int c = seg_hist[i * 16];
      seg_off[i] = eo; cur_seg[i * 16] = eo;
      eo += c;
    }
    if (hi == NSEG) seg_off[NSEG] = eo;         // == N_EDGES
    return;
  }
  // ---- dst slot-region allocation ----
  __shared__ int wbase[4];
  int tid = threadIdx.x, lane = tid & 63, wv = tid >> 6;
  int n = blockIdx.x * 256 + tid;
  int v = (n < N_NODES) ? hist_dst[n] : 0;
  int x = v;
  #pragma unroll
  for (int o = 1; o < 64; o <<= 1) { int u = __shfl_up(x, o); if (lane >= o) x += u; }
  if (lane == 63) wbase[wv] = atomicAdd(gcnt, x);   // x = wave total
  __syncthreads();
  int start = wbase[wv] + x - v;
  if (n < N_NODES) { dstart[n] = start; cur_dst[n] = start; }
}

// Scatter edges into perm, grouped by (src-bucket, rel). One atomic, 4B write.
__global__ __launch_bounds__(256) void k_scatter(const int* __restrict__ src,
                                                 const int* __restrict__ et,
                                                 int* __restrict__ cur_seg,
                                                 int* __restrict__ perm){
  int e = blockIdx.x * 256 + threadIdx.x;
  if (e >= N_EDGES) return;
  int key = (src[e] >> BSH) * N_RELS + et[e];
  int p = atomicAdd(&cur_seg[key * 16], 1);
  perm[p] = e;
}

// Blocks < NSEG: one (src-bucket, rel) SEGMENT per block — B staged once, then
// a NON-PIPELINED loop over the segment's 128-edge tiles (R2's proven per-tile
// body: slot atomic early, A-gather, MFMA, posIds, barrier, coalesced writeout,
// barrier; no cross-iteration prefetch state -> no race surface).
// Blocks >= NSEG: dense self-loop GEMM -> agg1b (bf16 wave-stripe, R8-verified).
__global__ __launch_bounds__(256, 4) void k_se1(
    const u16* __restrict__ featb, const u16* __restrict__ W1Tb,
    const u16* __restrict__ loop1Tb, const float* __restrict__ b1,
    const int* __restrict__ src, const int* __restrict__ dst,
    const int* __restrict__ perm, const int* __restrict__ seg_off,
    int* __restrict__ cur_dst, int* __restrict__ srel,
    u16* __restrict__ msgbuf, u16* __restrict__ agg1b){
  __shared__ __align__(16) u16 Bls[64][136];    // 17408 B
  __shared__ __align__(16) u16 msg[128][72];    // 18432 B
  __shared__ int posIds[128];
  int tid = threadIdx.x, lane = tid & 63, w4 = tid >> 6;
  int r16 = lane & 15, c4 = lane >> 4;

  if (blockIdx.x >= NSEG) {                     // ---- self-loop path ----
    int base = (blockIdx.x - NSEG) * 64;
    { int j = tid >> 2, sg = tid & 3;
      const uint4* g = (const uint4*)(loop1Tb + j * 128) + sg * 4;
      uint4* d = (uint4*)&Bls[j][sg * 32];
      d[0] = g[0]; d[1] = g[1]; d[2] = g[2]; d[3] = g[3]; }
    int arow = base + w4 * 16 + r16; if (arow >= N_NODES) arow = N_NODES - 1;
    sfrag aF[4];
    #pragma unroll
    for (int kk = 0; kk < 4; ++kk)
      aF[kk] = *(const sfrag*)(featb + (size_t)arow * D_IN + kk * 32 + c4 * 8);
    __syncthreads();
    #pragma unroll
    for (int ct = 0; ct < 4; ++ct) {
      int col = ct * 16 + r16;
      f32x4 acc = {0.f, 0.f, 0.f, 0.f};
      #pragma unroll
      for (int kk = 0; kk < 4; ++kk) {
        sfrag bF = *(const sfrag*)&Bls[ct * 16 + r16][kk * 32 + c4 * 8];
        acc = __builtin_amdgcn_mfma_f32_16x16x32_bf16(aF[kk], bF, acc, 0, 0, 0);
      }
      float bias = b1[col];
      #pragma unroll
      for (int reg = 0; reg < 4; ++reg) {
        float v = acc[reg] + bias;
        float o = __shfl_xor(v, 1);
        if (!(lane & 1))
          *(u32*)&msg[w4 * 16 + c4 * 4 + reg][col] = pack2(v, o);   // wave stripe
      }
    }
    { int j = lane >> 2, q = lane & 3;          // wave-private 32B/thread flush
      int n = base + w4 * 16 + j;
      if (n < N_NODES) {
        const uint4* mr = (const uint4*)&msg[w4 * 16 + j][q * 16];
        uint4* d = (uint4*)(agg1b + (size_t)n * D_HID + q * 16);
        d[0] = mr[0]; d[1] = mr[1];
      } }
    return;
  }

  // ---- segment path (non-pipelined) ----
  const int q8 = NSEG >> 3, r8 = NSEG & 7;      // bijective XCD chunk map
  int xcd = blockIdx.x & 7, cidx = blockIdx.x >> 3;
  int seg = (xcd < r8 ? xcd * (q8 + 1) : r8 * (q8 + 1) + (xcd - r8) * q8) + cidx;
  int ts = seg_off[seg], c = seg_off[seg + 1] - ts;
  if (c == 0) return;
  int rel = seg - (seg / N_RELS) * N_RELS;      // seg % 19

  { // B tile: W1Tb[rel], 64 x 128 bf16, staged ONCE per segment
    int j = tid >> 2, sg = tid & 3;
    const uint4* g = (const uint4*)(W1Tb + ((size_t)rel * 64 + j) * 128) + sg * 4;
    uint4* d = (uint4*)&Bls[j][sg * 32];
    d[0] = g[0]; d[1] = g[1]; d[2] = g[2]; d[3] = g[3];
  }
  __syncthreads();                              // B ready

  for (int t0 = 0; t0 < c; t0 += 128) {
    int vc = c - t0; if (vc > 128) vc = 128;
    // slot atomic + srel EARLY (latency hidden under the A-gather + MFMA below)
    int myPos = -1;
    if (tid < 128 && tid < vc) {
      int e = perm[ts + t0 + tid];
      myPos = atomicAdd(&cur_dst[dst[e]], 1);
      srel[myPos] = (src[e] << 5) | rel;
    }
    // A fragments direct global->VGPR (featb L2-bucket-local)
    sfrag aF[2][4];
    #pragma unroll
    for (int mt = 0; mt < 2; ++mt) {
      int row = w4 * 32 + mt * 16 + r16;
      int rr = row < vc ? row : vc - 1;
      int s = src[perm[ts + t0 + rr]];
      const u16* ap = featb + (size_t)s * D_IN + c4 * 8;
      #pragma unroll
      for (int kk = 0; kk < 4; ++kk)
        aF[mt][kk] = *(const sfrag*)(ap + kk * 32);
    }
    #pragma unroll
    for (int ct = 0; ct < 4; ++ct) {
      sfrag bF[4];
      #pragma unroll
      for (int kk = 0; kk < 4; ++kk)
        bF[kk] = *(const sfrag*)&Bls[ct * 16 + r16][kk * 32 + c4 * 8];
      #pragma unroll
      for (int mt = 0; mt < 2; ++mt) {
        f32x4 acc = {0.f, 0.f, 0.f, 0.f};
        #pragma unroll
        for (int kk = 0; kk < 4; ++kk)
          acc = __builtin_amdgcn_mfma_f32_16x16x32_bf16(aF[mt][kk], bF[kk], acc, 0, 0, 0);
        #pragma unroll
        for (int reg = 0; reg < 4; ++reg) {
          float v = acc[reg];
          float o = __shfl_xor(v, 1);
          if (!(lane & 1)) {
            int orow = w4 * 32 + mt * 16 + c4 * 4 + reg;
            *(u32*)&msg[orow][ct * 16 + r16] = pack2(v, o);
          }
        }
      }
    }
    if (tid < 128) posIds[tid] = myPos;
    __syncthreads();
    { int row = tid >> 1, half = tid & 1;       // coalesced 64B/thread writeout
      int pos = posIds[row];
      if (pos >= 0) {
        const uint4* mr = (const uint4*)&msg[row][half * 32];
        uint4* d = (uint4*)(msgbuf + (size_t)pos * D_HID + half * 32);
        d[0] = mr[0]; d[1] = mr[1]; d[2] = mr[2]; d[3] = mr[3];
      } }
    __syncthreads();                            // msg free for next tile
  }
}

// Fused: message aggregation (one node per wave, sequential msgbuf read) +
// self-loop + relu -> h1 (LDS f32, wave-private), then T2 row via 40-lane dot:
// T2[n][2r+o] = h1[n]@W2[r][:,o]; cols 38/39 carry loop2 -> out init (+b2).
__global__ __launch_bounds__(256) void k_agg(
    const u16* __restrict__ msgbuf, const int* __restrict__ dstart,
    const int* __restrict__ cnt, const u16* __restrict__ agg1b,
    const u16* __restrict__ W2allT, const float* __restrict__ b2,
    float* __restrict__ T2f, float* __restrict__ out){
  __shared__ u16   W2ls[64][66];                // padded: bank-spread rows
  __shared__ float h1s[4][68];
  int tid = threadIdx.x, wv = tid >> 6, lane = tid & 63;
  for (int i = tid; i < 64 * 64; i += 256) W2ls[i >> 6][i & 63] = W2allT[i];
  int n = blockIdx.x * 4 + wv;
  int s = dstart[n], epos = s + cnt[n];
  int h = lane >> 5, cc = lane & 31;
  float a0 = 0.f, a1 = 0.f;
  for (int i = s + h; i < epos; i += 2) {
    u32 v = ((const u32*)msgbuf)[(size_t)i * 32 + cc];
    a0 += bf2f((u16)(v & 0xffffu));
    a1 += bf2f((u16)(v >> 16));
  }
  a0 += __shfl_down(a0, 32);
  a1 += __shfl_down(a1, 32);
  if (h == 0) {
    u32 sv = ((const u32*)agg1b)[(size_t)n * 32 + cc];
    float v0 = a0 + bf2f((u16)(sv & 0xffffu));
    float v1 = a1 + bf2f((u16)(sv >> 16));
    v0 = v0 > 0.f ? v0 : 0.f;
    v1 = v1 > 0.f ? v1 : 0.f;
    h1s[wv][2 * cc]     = v0;
    h1s[wv][2 * cc + 1] = v1;
  }
  __syncthreads();                              // W2ls visible (h1s wave-private)
  if (lane < 40) {
    float acc = 0.f;
    #pragma unroll 8
    for (int k = 0; k < 64; ++k)
      acc += bf2f(W2ls[lane][k]) * h1s[wv][k];
    if (lane < 38) T2f[(size_t)n * 40 + lane] = acc;
    else           out[n * 2 + (lane - 38)] = acc + b2[lane - 38];
  }
}

// Layer-2 finish: one wave per node; sequential srel read, 8B T2 gather per
// slot, reduce, add to out. No global atomics.
__global__ __launch_bounds__(256) void k_fin(
    const float* __restrict__ T2f, const int* __restrict__ srel,
    const int* __restrict__ dstart, const int* __restrict__ cnt,
    float* __restrict__ out){
  int wv = threadIdx.x >> 6, lane = threadIdx.x & 63;
  int n = blockIdx.x * 4 + wv;
  int s = dstart[n], c = cnt[n];
  float ax = 0.f, ay = 0.f;
  for (int i = lane; i < c; i += 64) {
    int sr = srel[s + i];
    const float* p = T2f + (size_t)(sr >> 5) * 40 + (sr & 31) * 2;
    ax += p[0]; ay += p[1];
  }
  #pragma unroll
  for (int off = 32; off; off >>= 1) {
    ax += __shfl_down(ax, off);
    ay += __shfl_down(ay, off);
  }
  if (lane == 0) {
    out[n * 2]     += ax;
    out[n * 2 + 1] += ay;
  }
}

extern "C" void kernel_launch(void* const* d_in, const int* in_sizes, int n_in,
                              void* d_out, int out_size, void* d_ws, size_t ws_size,
                              hipStream_t stream){
  const float* feat  = (const float*)d_in[0];
  const float* W1    = (const float*)d_in[1];
  const float* loop1 = (const float*)d_in[2];
  const float* b1    = (const float*)d_in[3];
  const float* W2    = (const float*)d_in[4];
  const float* loop2 = (const float*)d_in[5];
  const float* b2    = (const float*)d_in[6];
  const int* src     = (const int*)d_in[7];
  const int* dst     = (const int*)d_in[8];
  const int* et      = (const int*)d_in[9];
  float* out = (float*)d_out;

  // workspace layout (16B-aligned), ~102 MB total.
  char* w = (char*)d_ws;
  u16*   W1Tb     = (u16*)(w);                   //  311296
  u16*   W2allT   = (u16*)(w + 311296);          //    8192 (64x64 bf16)
  u16*   loop1Tb  = (u16*)(w + 319488);          //   16384
  int*   seg_hist = (int*)(w + 335872);          //  119168 (1862 x 64B) ┐
  int*   gcnt     = (int*)(w + 455040);          //      64              ├ memset (319232 B)
  int*   hist_dst = (int*)(w + 455104);          //  200000              ┘
  int*   seg_off  = (int*)(w + 655104);          //    7488
  int*   cur_seg  = (int*)(w + 662592);          //  119168 (64B-padded)
  int*   dstart   = (int*)(w + 781760);          //  200000
  int*   cur_dst  = (int*)(w + 981760);          //  200000
  int*   perm     = (int*)(w + 1181760);         // 2400000
  int*   srel     = (int*)(w + 3581760);         // 2400000
  u16*   featb    = (u16*)(w + 5981760);         // 12.8 MB (T2f aliases; featb dead after k_se1)
  float* T2f      = (float*)(w + 5981760);       //  8.0 MB (50000 x 40 f32)
  u16*   agg1b    = (u16*)(w + 18781760);        //  6.4 MB
  u16*   msgbuf   = (u16*)(w + 25181760);        // 76.8 MB -> 101981760

  hipMemsetAsync(w + 335872, 0, 319232, stream);
  k_pre     <<<6250, 256, 0, stream>>>(feat, featb, src, et, dst, seg_hist, hist_dst);
  k_prep    <<<197 + PREP_BLOCKS, 256, 0, stream>>>(
                hist_dst, dstart, cur_dst, gcnt, seg_hist, seg_off, cur_seg,
                W1, loop1, W2, loop2, W1Tb, loop1Tb, W2allT);
  k_scatter <<<2344, 256, 0, stream>>>(src, et, cur_seg, perm);
  k_se1     <<<NSEG + SL_BLOCKS, 256, 0, stream>>>(
                featb, W1Tb, loop1Tb, b1, src, dst, perm, seg_off,
                cur_dst, srel, msgbuf, agg1b);
  k_agg     <<<12500, 256, 0, stream>>>(msgbuf, dstart, hist_dst, agg1b,
                                        W2allT, b2, T2f, out);
  k_fin     <<<12500, 256, 0, stream>>>(T2f, srel, dstart, hist_dst, out);
}